// Round 20
// baseline (148.660 us; speedup 1.0000x reference)
//
#include <hip/hip_runtime.h>
#include <hip/hip_bf16.h>
#include <hip/hip_fp16.h>

// Problem constants
#define BB 8
#define HH 56
#define WW 56
#define CC 384
#define NHD 6
#define DD 64
#define HK 28
#define WK 28
#define NQ (HH*WW)       // 3136
#define NKV (HK*WK)      // 784
#define NTOK (BB*NQ)     // 25088
#define NTOKKV (BB*NKV)  // 6272
#define BN_EPS 1e-5f
#define LOG2E 1.44269504f

typedef _Float16 f16;
typedef _Float16 f16x2 __attribute__((ext_vector_type(2)));
typedef _Float16 f16x4 __attribute__((ext_vector_type(4)));
typedef _Float16 f16x8 __attribute__((ext_vector_type(8)));
typedef float f32x4 __attribute__((ext_vector_type(4)));

__device__ __forceinline__ float fast_exp2(float x) {
#if __has_builtin(__builtin_amdgcn_exp2f)
  return __builtin_amdgcn_exp2f(x);   // v_exp_f32 (2^x)
#else
  return __expf(x * 0.69314718056f);
#endif
}

__device__ __forceinline__ f16x4 pack4(float p0, float p1, float p2, float p3) {
#if __has_builtin(__builtin_amdgcn_cvt_pkrtz)
  f16x2 a = __builtin_bit_cast(f16x2, __builtin_amdgcn_cvt_pkrtz(p0, p1));
  f16x2 b = __builtin_bit_cast(f16x2, __builtin_amdgcn_cvt_pkrtz(p2, p3));
  return __builtin_shufflevector(a, b, 0, 1, 2, 3);
#else
  f16x4 r; r[0] = (f16)p0; r[1] = (f16)p1; r[2] = (f16)p2; r[3] = (f16)p3;
  return r;
#endif
}

// ---------------- dw conv + BN bodies (high-ILP: all loads hoisted) ----------------
// dw_s1: 2x2 output quad per thread. 16 input float4 + 9 weight float4 up-front.
__device__ __forceinline__ void dw_s1_body(
    int blk, int tid, const float* __restrict__ in, const float* __restrict__ w,
    const float* __restrict__ bns, const float* __restrict__ bnb,
    const float* __restrict__ bnm, const float* __restrict__ bnv,
    f16* __restrict__ out) {
  int idx = blk * 256 + tid;                     // < 602112 = (NTOK/4)*96
  int pp = idx / 96;
  int c = (idx % 96) * 4;
  int b = pp / 784;                              // 28*28 quads per image
  int rem = pp % 784;
  int yh = rem / 28, xh = rem % 28;
  int y0 = yh * 2, x0 = xh * 2;
  const float4 z4 = {0.f, 0.f, 0.f, 0.f};

  float4 V[4][4];
#pragma unroll
  for (int ry = 0; ry < 4; ++ry) {
    const int iy = y0 - 1 + ry;
    const bool vy = (unsigned)iy < (unsigned)HH;
    const float* rp = in + ((size_t)(b * HH + (vy ? iy : 0)) * WW) * CC + c;
    V[ry][0] = (vy && x0 > 0)      ? *(const float4*)(rp + (size_t)(x0 - 1) * CC) : z4;
    V[ry][1] = vy                  ? *(const float4*)(rp + (size_t)x0 * CC)       : z4;
    V[ry][2] = vy                  ? *(const float4*)(rp + (size_t)(x0 + 1) * CC) : z4;
    V[ry][3] = (vy && x0 < WW - 2) ? *(const float4*)(rp + (size_t)(x0 + 2) * CC) : z4;
  }
  float4 W[9];
#pragma unroll
  for (int i = 0; i < 9; ++i) W[i] = *(const float4*)(w + i * CC + c);

  const float4 s = *(const float4*)(bns + c);
  const float4 bi = *(const float4*)(bnb + c);
  const float4 m = *(const float4*)(bnm + c);
  const float4 va = *(const float4*)(bnv + c);
  const float gx = s.x * rsqrtf(va.x + BN_EPS);
  const float gy = s.y * rsqrtf(va.y + BN_EPS);
  const float gz = s.z * rsqrtf(va.z + BN_EPS);
  const float gw = s.w * rsqrtf(va.w + BN_EPS);

#pragma unroll
  for (int dy = 0; dy < 2; ++dy)
#pragma unroll
    for (int dx = 0; dx < 2; ++dx) {
      float ax = 0.f, ay = 0.f, az = 0.f, aw = 0.f;
#pragma unroll
      for (int ky = 0; ky < 3; ++ky)
#pragma unroll
        for (int kx = 0; kx < 3; ++kx) {
          const float4 v = V[dy + ky][dx + kx];
          const float4 wk = W[ky * 3 + kx];
          ax = fmaf(v.x, wk.x, ax); ay = fmaf(v.y, wk.y, ay);
          az = fmaf(v.z, wk.z, az); aw = fmaf(v.w, wk.w, aw);
        }
      f16x4 r;
      r[0] = (f16)fmaf(ax - m.x, gx, bi.x);
      r[1] = (f16)fmaf(ay - m.y, gy, bi.y);
      r[2] = (f16)fmaf(az - m.z, gz, bi.z);
      r[3] = (f16)fmaf(aw - m.w, gw, bi.w);
      const size_t pix = (size_t)b * NQ + (size_t)(y0 + dy) * WW + (x0 + dx);
      *(f16x4*)(out + pix * CC + c) = r;
    }
}

// dw_s2 (stride 2): 2 adjacent output pixels per thread; 15 input float4 shared
// between both outputs AND both (k,v) weight sets.
__device__ __forceinline__ void dw_s2_body(
    int blk, int tid, const float* __restrict__ in,
    const float* __restrict__ wk_, const float* __restrict__ kbs, const float* __restrict__ kbb,
    const float* __restrict__ kbm, const float* __restrict__ kbv,
    const float* __restrict__ wv_, const float* __restrict__ vbs, const float* __restrict__ vbb,
    const float* __restrict__ vbm, const float* __restrict__ vbv,
    f16* __restrict__ outk, f16* __restrict__ outv) {
  int idx = blk * 256 + tid;                     // < 301056 = (NTOKKV/2)*96
  int pp = idx / 96;
  int c = (idx % 96) * 4;
  int b = pp / 392;                              // 28*14 pairs per image
  int rem = pp % 392;
  int oy = rem / 14, xh = rem % 14;
  int ox0 = xh * 2;
  int iy0 = oy * 2, ix0 = ox0 * 2;
  const float4 z4 = {0.f, 0.f, 0.f, 0.f};

  float4 V[3][5];
#pragma unroll
  for (int ry = 0; ry < 3; ++ry) {
    const int iy = iy0 + ry;
    const bool vy = iy < HH;
    const float* rp = in + ((size_t)(b * HH + (vy ? iy : 0)) * WW) * CC + c;
#pragma unroll
    for (int cx = 0; cx < 5; ++cx) {
      const int ix = ix0 + cx;
      V[ry][cx] = (vy && ix < WW) ? *(const float4*)(rp + (size_t)ix * CC) : z4;
    }
  }

  // ---- k path ----
  {
    float4 W[9];
#pragma unroll
    for (int i = 0; i < 9; ++i) W[i] = *(const float4*)(wk_ + i * CC + c);
    const float4 s = *(const float4*)(kbs + c);
    const float4 bi = *(const float4*)(kbb + c);
    const float4 m = *(const float4*)(kbm + c);
    const float4 va = *(const float4*)(kbv + c);
    const float gx = s.x * rsqrtf(va.x + BN_EPS);
    const float gy = s.y * rsqrtf(va.y + BN_EPS);
    const float gz = s.z * rsqrtf(va.z + BN_EPS);
    const float gw = s.w * rsqrtf(va.w + BN_EPS);
#pragma unroll
    for (int dx = 0; dx < 2; ++dx) {
      float ax = 0.f, ay = 0.f, az = 0.f, aw = 0.f;
#pragma unroll
      for (int ky = 0; ky < 3; ++ky)
#pragma unroll
        for (int kx = 0; kx < 3; ++kx) {
          const float4 v = V[ky][2 * dx + kx];
          const float4 wk = W[ky * 3 + kx];
          ax = fmaf(v.x, wk.x, ax); ay = fmaf(v.y, wk.y, ay);
          az = fmaf(v.z, wk.z, az); aw = fmaf(v.w, wk.w, aw);
        }
      f16x4 r;
      r[0] = (f16)fmaf(ax - m.x, gx, bi.x);
      r[1] = (f16)fmaf(ay - m.y, gy, bi.y);
      r[2] = (f16)fmaf(az - m.z, gz, bi.z);
      r[3] = (f16)fmaf(aw - m.w, gw, bi.w);
      const size_t pix = (size_t)b * NKV + (size_t)oy * WK + (ox0 + dx);
      *(f16x4*)(outk + pix * CC + c) = r;
    }
  }
  // ---- v path (reuses V) ----
  {
    float4 W[9];
#pragma unroll
    for (int i = 0; i < 9; ++i) W[i] = *(const float4*)(wv_ + i * CC + c);
    const float4 s = *(const float4*)(vbs + c);
    const float4 bi = *(const float4*)(vbb + c);
    const float4 m = *(const float4*)(vbm + c);
    const float4 va = *(const float4*)(vbv + c);
    const float gx = s.x * rsqrtf(va.x + BN_EPS);
    const float gy = s.y * rsqrtf(va.y + BN_EPS);
    const float gz = s.z * rsqrtf(va.z + BN_EPS);
    const float gw = s.w * rsqrtf(va.w + BN_EPS);
#pragma unroll
    for (int dx = 0; dx < 2; ++dx) {
      float ax = 0.f, ay = 0.f, az = 0.f, aw = 0.f;
#pragma unroll
      for (int ky = 0; ky < 3; ++ky)
#pragma unroll
        for (int kx = 0; kx < 3; ++kx) {
          const float4 v = V[ky][2 * dx + kx];
          const float4 wk = W[ky * 3 + kx];
          ax = fmaf(v.x, wk.x, ax); ay = fmaf(v.y, wk.y, ay);
          az = fmaf(v.z, wk.z, az); aw = fmaf(v.w, wk.w, aw);
        }
      f16x4 r;
      r[0] = (f16)fmaf(ax - m.x, gx, bi.x);
      r[1] = (f16)fmaf(ay - m.y, gy, bi.y);
      r[2] = (f16)fmaf(az - m.z, gz, bi.z);
      r[3] = (f16)fmaf(aw - m.w, gw, bi.w);
      const size_t pix = (size_t)b * NKV + (size_t)oy * WK + (ox0 + dx);
      *(f16x4*)(outv + pix * CC + c) = r;
    }
  }
}

// ---- fused preprocess: dw_s1 (2352) + dw_s2_kv (1176) + convert_w (576) ----
// Segments XCD-chunked (contiguous image span per XCD).
__global__ __launch_bounds__(256) void preprocess(
    const float* __restrict__ inputs_q, const float* __restrict__ inputs_kv,
    const float* __restrict__ q_dwk, const float* __restrict__ q_bs,
    const float* __restrict__ q_bb, const float* __restrict__ q_bm,
    const float* __restrict__ q_bv,
    const float* __restrict__ k_dwk, const float* __restrict__ k_bs,
    const float* __restrict__ k_bb, const float* __restrict__ k_bm,
    const float* __restrict__ k_bv,
    const float* __restrict__ v_dwk, const float* __restrict__ v_bs,
    const float* __restrict__ v_bb, const float* __restrict__ v_bm,
    const float* __restrict__ v_bv,
    const float* __restrict__ w0, const float* __restrict__ w1,
    const float* __restrict__ w2, const float* __restrict__ w3,
    f16* __restrict__ o0, f16* __restrict__ o1,
    f16* __restrict__ o2, f16* __restrict__ o3,
    f16* __restrict__ qdw, f16* __restrict__ kdw, f16* __restrict__ vdw) {
  __shared__ float t[32][33];
  const int bid = blockIdx.x;
  const int tid = threadIdx.x;
  if (bid < 2352) {
    const int lb = (bid & 7) * 294 + (bid >> 3);        // 2352 = 8*294, bijective
    dw_s1_body(lb, tid, inputs_q, q_dwk, q_bs, q_bb, q_bm, q_bv, qdw);
  } else if (bid < 3528) {
    const int r = bid - 2352;                           // 1176 = 8*147
    const int lb = (r & 7) * 147 + (r >> 3);
    dw_s2_body(lb, tid, inputs_kv,
               k_dwk, k_bs, k_bb, k_bm, k_bv,
               v_dwk, v_bs, v_bb, v_bm, v_bv, kdw, vdw);
  } else {
    const int r = bid - 3528;                 // 0..575  (12 x 12 x 4)
    const int z = r / 144, rem = r % 144;
    const int bx = rem % 12, by = rem / 12;
    const float* src = z == 0 ? w0 : z == 1 ? w1 : z == 2 ? w2 : w3;
    f16* dst = z == 0 ? o0 : z == 1 ? o1 : z == 2 ? o2 : o3;
    const int k0 = bx * 32, n0 = by * 32;
    const int x = tid & 31, y = tid >> 5;
#pragma unroll
    for (int i = 0; i < 4; ++i) t[y + i * 8][x] = src[(size_t)(k0 + y + i * 8) * 384 + n0 + x];
    __syncthreads();
#pragma unroll
    for (int i = 0; i < 4; ++i)
      dst[(size_t)(n0 + y + i * 8) * 384 + k0 + x] = (f16)t[x][y + i * 8];
  }
}

// ------------- f16 MFMA GEMM body (128x128 tile, BK=64, 4 waves, 4x4 frags) -------------
// MODE 0: fp32 row-major; MODE 1: f16 row-major; MODE 2: f16 V^T (vtp [b*384+d][784])
template <int MODE>
__device__ __forceinline__ void gemm_body(
    const f16* __restrict__ A, const f16* __restrict__ Bt,
    float* __restrict__ Cf, f16* __restrict__ Ch, float scale,
    int row0, int col0) {
  __shared__ f16 As[128 * 64];   // [row][k], 128 B per row
  __shared__ f16 Bs[128 * 64];   // [col][k], 128 B per col
  const int tid = threadIdx.x;
  const int wave = tid >> 6, lane = tid & 63;
  const int c = lane & 15, g = lane >> 4;
  const int wr = wave >> 1, wc = wave & 1;     // 2x2 waves, each 64x64

  const int s_base = wave * 64 + lane;
  f32x4 acc[4][4] = {};

  for (int k0 = 0; k0 < 384; k0 += 64) {
    __syncthreads();
#pragma unroll
    for (int j = 0; j < 4; ++j) {
      const int s = j * 256 + s_base;
      const int row = s >> 3, sch = s & 7;
      const int lch = sch ^ (row & 7);         // logical k-chunk fetched
      const f16* sa = A + (size_t)(row0 + row) * 384 + k0 + lch * 8;
      __builtin_amdgcn_global_load_lds(
          (const __attribute__((address_space(1))) void*)sa,
          (__attribute__((address_space(3))) void*)(As + j * 2048 + wave * 512), 16, 0, 0);
      const f16* sb = Bt + (size_t)(col0 + row) * 384 + k0 + lch * 8;
      __builtin_amdgcn_global_load_lds(
          (const __attribute__((address_space(1))) void*)sb,
          (__attribute__((address_space(3))) void*)(Bs + j * 2048 + wave * 512), 16, 0, 0);
    }
    __syncthreads();

#pragma unroll
    for (int kh = 0; kh < 2; ++kh) {
      f16x8 bf[4];
#pragma unroll
      for (int n = 0; n < 4; ++n) {
        const int row = wc * 64 + n * 16 + c;
        bf[n] = *(const f16x8*)(Bs + (size_t)row * 64 + ((kh * 4 + g) ^ (row & 7)) * 8);
      }
#pragma unroll
      for (int m = 0; m < 4; ++m) {
        const int row = wr * 64 + m * 16 + c;
        f16x8 af = *(const f16x8*)(As + (size_t)row * 64 + ((kh * 4 + g) ^ (row & 7)) * 8);
#pragma unroll
        for (int n = 0; n < 4; ++n)
          acc[m][n] = __builtin_amdgcn_mfma_f32_16x16x32_f16(af, bf[n], acc[m][n], 0, 0, 0);
      }
    }
  }

  if (MODE == 2) {
#pragma unroll
    for (int m = 0; m < 4; ++m)
#pragma unroll
      for (int n = 0; n < 4; ++n) {
        const int gr = row0 + wr * 64 + m * 16 + g * 4;
        const int col = col0 + wc * 64 + n * 16 + c;
        const int bb = gr / NKV;
        const int kv = gr - bb * NKV;           // 4-pack cannot cross batch (784%4==0, gr%4==0)
        f16x4 pk;
#pragma unroll
        for (int r = 0; r < 4; ++r) pk[r] = (f16)(acc[m][n][r] * scale);
        *(f16x4*)(Ch + ((size_t)bb * 384 + col) * NKV + kv) = pk;
      }
  } else {
#pragma unroll
    for (int m = 0; m < 4; ++m)
#pragma unroll
      for (int n = 0; n < 4; ++n)
#pragma unroll
        for (int r = 0; r < 4; ++r) {
          const size_t row = row0 + wr * 64 + m * 16 + g * 4 + r;
          const size_t col = col0 + wc * 64 + n * 16 + c;
          if (MODE == 1) Ch[row * 384 + col] = (f16)(acc[m][n][r] * scale);
          else           Cf[row * 384 + col] = acc[m][n][r] * scale;
        }
  }
}

// fused q/k/v pointwise GEMMs: 882 flat blocks = q(196x3) + k(49x3) + v(49x3)
__global__ __launch_bounds__(256) void gemm_qkv(
    const f16* __restrict__ qdw, const f16* __restrict__ wqt, f16* __restrict__ qf, float qscale,
    const f16* __restrict__ kdw, const f16* __restrict__ wkt, f16* __restrict__ kf,
    const f16* __restrict__ vdw, const f16* __restrict__ wvt, f16* __restrict__ vtp) {
  const int blk = blockIdx.x;
  if (blk < 588) {
    gemm_body<1>(qdw, wqt, nullptr, qf, qscale, (blk % 196) * 128, (blk / 196) * 128);
  } else if (blk < 735) {
    const int r = blk - 588;
    gemm_body<1>(kdw, wkt, nullptr, kf, 1.0f, (r % 49) * 128, (r / 49) * 128);
  } else {
    const int r = blk - 735;
    gemm_body<2>(vdw, wvt, nullptr, vtp, 1.0f, (r % 49) * 128, (r / 49) * 128);
  }
}

template <int MODE>
__global__ __launch_bounds__(256) void gemm_mfma(
    const f16* __restrict__ A, const f16* __restrict__ Bt,
    float* __restrict__ Cf, f16* __restrict__ Ch, float scale) {
  gemm_body<MODE>(A, Bt, Cf, Ch, scale, blockIdx.x * 128, blockIdx.y * 128);
}

// ------------- f16 MFMA flash attention: single-buffer T14 + high occupancy -------------
// grid = 2352; lb = (bid&7)*294 + (bid>>3): each XCD owns 6 complete (b,h) pairs.
// LDS 24.5KB -> 6 blocks/CU; __launch_bounds__(256,6) requests 6 waves/SIMD residency.
// T14: K/V in regs during previous tile's compute; 2 barriers/tile (proven-neutral
// vs 1-barrier dbuf in R19, and single buffer keeps LDS small for occupancy).
__global__ __launch_bounds__(256, 6) void attn_mfma(
    const f16* __restrict__ qp, const f16* __restrict__ kp,
    const f16* __restrict__ vt, f16* __restrict__ op) {
  __shared__ f16 Ks[64 * 64];      // [kv][d], chunk ch at ch^(kv&7)
  __shared__ f16 Vs[64 * 64];      // [d][kv], chunk ch at ch^(d&7)
  __shared__ f16 Ps[4][16 * 64];   // per-wave [q][kv], ch^(q&7)
  const int bid0 = blockIdx.x;
  const int lb = (bid0 & 7) * 294 + (bid0 >> 3);   // bijective (2352 = 8*294)
  const int qt = lb % 49;
  const int bh = lb / 49;
  const int h = bh % NHD, b = bh / NHD;
  const int tid = threadIdx.x;
  const int wave = tid >> 6, lane = tid & 63;
  const int c = lane & 15, g = lane >> 4;

  const size_t qrow = (size_t)b * NQ + qt * 64 + wave * 16 + c;
  f16x8 qa[2];
  qa[0] = *(const f16x8*)(qp + qrow * 384 + h * 64 + g * 8);
  qa[1] = *(const f16x8*)(qp + qrow * 384 + h * 64 + 32 + g * 8);

  f16x8 vones;
#pragma unroll
  for (int j = 0; j < 8; ++j) vones[j] = (f16)1.0f;

  const int tid8 = tid >> 3, tch = tid & 7;
  const int lch = tch ^ (tid8 & 7);            // logical chunk fetched

  const f16* kbase = kp + ((size_t)b * NKV) * 384 + h * 64;
  const f16* vbase = vt + ((size_t)(b * 384 + h * 64)) * NKV;

  float mrun = -1e30f;                // for q = c (redundant across g)
  f32x4 o[4] = {};                    // O[q=g*4+r][d=dt*16+c]
  f32x4 osum = {};                    // lsum[q=g*4+r]
  f16* prow = &Ps[wave][0];

  // T14 staging registers + preload tile 0 (in-bounds at t0=0)
  f16x8 kr0, kr1, vr0, vr1;
  kr0 = *(const f16x8*)(kbase + (size_t)tid8 * 384 + lch * 8);
  kr1 = *(const f16x8*)(kbase + (size_t)(32 + tid8) * 384 + lch * 8);
  vr0 = *(const f16x8*)(vbase + (size_t)tid8 * NKV + lch * 8);
  vr1 = *(const f16x8*)(vbase + (size_t)(32 + tid8) * NKV + lch * 8);

  for (int ti = 0; ti < 13; ++ti) {
    __syncthreads();                  // all waves done reading LDS (prev tile)
    *(f16x8*)(Ks + tid * 8) = kr0;
    *(f16x8*)(Ks + 2048 + tid * 8) = kr1;
    *(f16x8*)(Vs + tid * 8) = vr0;
    *(f16x8*)(Vs + 2048 + tid * 8) = vr1;
    if (ti + 1 < 13) {
      const int t0n = (ti + 1) * 64;
      int kvA = t0n + tid8;        if (kvA > NKV - 1) kvA = NKV - 1;
      int kvB = t0n + 32 + tid8;   if (kvB > NKV - 1) kvB = NKV - 1;
      int colc = t0n + lch * 8;    if (colc > NKV - 8) colc = NKV - 8;
      kr0 = *(const f16x8*)(kbase + (size_t)kvA * 384 + lch * 8);
      kr1 = *(const f16x8*)(kbase + (size_t)kvB * 384 + lch * 8);
      vr0 = *(const f16x8*)(vbase + (size_t)tid8 * NKV + colc);
      vr1 = *(const f16x8*)(vbase + (size_t)(32 + tid8) * NKV + colc);
    }
    __syncthreads();                  // LDS writes visible to all waves

    if (ti < 12) {
      // -------- full tile --------
      f32x4 s[4] = {};
      __builtin_amdgcn_s_setprio(1);
#pragma unroll
      for (int kh = 0; kh < 2; ++kh) {
#pragma unroll
        for (int ct = 0; ct < 4; ++ct) {
          const int row = ct * 16 + c;
          const int sch = (kh * 4 + g) ^ (row & 7);
          f16x8 kb = *(const f16x8*)(Ks + row * 64 + sch * 8);
          s[ct] = __builtin_amdgcn_mfma_f32_16x16x32_f16(kb, qa[kh], s[ct], 0, 0, 0);
        }
      }
      __builtin_amdgcn_s_setprio(0);

      float mt = s[0][0];
#pragma unroll
      for (int ct = 0; ct < 4; ++ct)
#pragma unroll
        for (int r = 0; r < 4; ++r) mt = fmaxf(mt, s[ct][r]);
      mt = fmaxf(mt, __shfl_xor(mt, 16));
      mt = fmaxf(mt, __shfl_xor(mt, 32));

      if (__ballot(mt > mrun + 8.0f)) {   // defer-max: P bounded by 2^8
        const float mnew = fmaxf(mrun, mt);
        const float corr = fast_exp2(mrun - mnew);
        mrun = mnew;
#pragma unroll
        for (int r = 0; r < 4; ++r) {
          const float co = __shfl(corr, g * 4 + r);
#pragma unroll
          for (int dt = 0; dt < 4; ++dt) o[dt][r] *= co;
          osum[r] *= co;
        }
      }

#pragma unroll
      for (int ct = 0; ct < 4; ++ct) {
        const float p0 = fast_exp2(s[ct][0] - mrun);
        const float p1 = fast_exp2(s[ct][1] - mrun);
        const float p2 = fast_exp2(s[ct][2] - mrun);
        const float p3 = fast_exp2(s[ct][3] - mrun);
        const int sch = (ct * 2 + (g >> 1)) ^ (c & 7);
        *(f16x4*)(prow + c * 64 + sch * 8 + (g & 1) * 4) = pack4(p0, p1, p2, p3);
      }

      __builtin_amdgcn_s_setprio(1);
#pragma unroll
      for (int ks = 0; ks < 2; ++ks) {
        const int sp = (ks * 4 + g) ^ (c & 7);
        f16x8 pa = *(const f16x8*)(prow + c * 64 + sp * 8);
#pragma unroll
        for (int dt = 0; dt < 4; ++dt) {
          const int d = dt * 16 + c;
          f16x8 vb = *(const f16x8*)(Vs + d * 64 + sp * 8);
          o[dt] = __builtin_amdgcn_mfma_f32_16x16x32_f16(pa, vb, o[dt], 0, 0, 0);
        }
        osum = __builtin_amdgcn_mfma_f32_16x16x32_f16(pa, vones, osum, 0, 0, 0);
      }
      __builtin_amdgcn_s_setprio(0);
    } else {
      // -------- tail tile: t0 = 768, only 16 valid KV rows --------
      f32x4 s0 = {};
      __builtin_amdgcn_s_setprio(1);
#pragma unroll
      for (int kh = 0; kh < 2; ++kh) {
        const int sch = (kh * 4 + g) ^ (c & 7);
        f16x8 kb = *(const f16x8*)(Ks + c * 64 + sch * 8);
        s0 = __builtin_amdgcn_mfma_f32_16x16x32_f16(kb, qa[kh], s0, 0, 0, 0);
      }
      __builtin_amdgcn_s_setprio(0);

      float mt = fmaxf(fmaxf(s0[0], s0[1]), fmaxf(s0[2], s0[3]));
      mt = fmaxf(mt, __shfl_xor(mt, 16));
      mt = fmaxf(mt, __shfl_xor(mt, 32));
      if (__ballot(mt > mrun + 8.0f)) {
        const float mnew = fmaxf(mrun, mt);
        const float corr = fast_exp2(mrun - mnew);
        mrun = mnew;
#pragma unroll
        for (int r = 0; r < 4; ++r) {
          const float co = __shfl(corr, g * 4 + r);
#pragma unroll
          for (int dt = 0; dt < 4; ++dt) o[dt][r] *= co;
          osum[r] *= co;
        }
      }

      {
        const float p0 = fast_exp2(s0[0] - mrun);
        const float p1 = fast_exp2(s0[1] - mrun);
        const float p2 = fast_exp2(s0[2] - mrun);
        const float p3 = fast_exp2(s0[3] - mrun);
        const int sch0 = (0 + (g >> 1)) ^ (c & 7);
        *(f16x4*)(prow + c * 64 + sch0 * 8 + (g & 1) * 4) = pack4(p0, p1, p2, p3);
        const int sch1 = (2 + (g >> 1)) ^ (c & 7);
        f16x4 z = {};
        *(f16x4*)(prow + c * 64 + sch1 * 8 + (g & 1) * 4) = z;
      }

      __builtin_amdgcn_s_setprio(1);
      {
        const int sp = g ^ (c & 7);
        f16x8 pa = *(const f16x8*)(prow + c * 64 + sp * 8);
#pragma unroll
        for (int dt = 0; dt < 4; ++dt) {
          const int d = dt * 16 + c;
          f16x8 vb = *(const f16x8*)(Vs + d * 64 + sp * 8);
          o[dt] = __builtin_amdgcn_mfma_f32_16x16x32_f16(pa, vb, o[dt], 0, 0, 0);
        }
        osum = __builtin_amdgcn_mfma_f32_16x16x32_f16(pa, vones, osum, 0, 0, 0);
      }
      __builtin_amdgcn_s_setprio(0);
    }
  }

  // epilogue: osum already in q=g*4+r row layout -> no shuffles
  f16* obase = op + ((size_t)(b * NQ + qt * 64 + wave * 16)) * 384 + h * 64;
#pragma unroll
  for (int r = 0; r < 4; ++r) {
    const float iv = 1.0f / osum[r];
#pragma unroll
    for (int dt = 0; dt < 4; ++dt)
      obase[(size_t)(g * 4 + r) * 384 + dt * 16 + c] = (f16)(o[dt][r] * iv);
  }
}

extern "C" void kernel_launch(void* const* d_in, const int* in_sizes, int n_in,
                              void* d_out, int out_size, void* d_ws, size_t ws_size,
                              hipStream_t stream) {
  const float* inputs_q  = (const float*)d_in[0];
  const float* inputs_kv = (const float*)d_in[1];
  const float* out_kern  = (const float*)d_in[2];
  const float* q_dwk = (const float*)d_in[3];
  const float* q_bs  = (const float*)d_in[4];
  const float* q_bb  = (const float*)d_in[5];
  const float* q_bm  = (const float*)d_in[6];
  const float* q_bv  = (const float*)d_in[7];
  const float* q_pwk = (const float*)d_in[8];
  const float* k_dwk = (const float*)d_in[9];
  const float* k_bs  = (const float*)d_in[10];
  const float* k_bb  = (const float*)d_in[11];
  const float* k_bm  = (const float*)d_in[12];
  const float* k_bv  = (const float*)d_in[13];
  const float* k_pwk = (const float*)d_in[14];
  const float* v_dwk = (const float*)d_in[15];
  const float* v_bs  = (const float*)d_in[16];
  const float* v_bb  = (const float*)d_in[17];
  const float* v_bm  = (const float*)d_in[18];
  const float* v_bv  = (const float*)d_in[19];
  const float* v_pwk = (const float*)d_in[20];

  char* wsb = (char*)d_ws;
  f16* qdw = (f16*)(wsb + 0);             // 25088*384 f16
  f16* kdw = (f16*)(wsb + 19267584);      // 6272*384 f16
  f16* vdw = (f16*)(wsb + 24084480);      // 6272*384 f16
  f16* qf  = (f16*)(wsb + 28901376);      // 25088*384 f16
  f16* kf  = (f16*)(wsb + 48168960);      // 6272*384 f16
  f16* vtp = (f16*)(wsb + 57802752);      // 8*384*784 f16
  f16* of  = (f16*)(wsb + 62619648);      // 25088*384 f16
  f16* wqt = (f16*)(wsb + 81887232);      // 384*384 f16 x4
  f16* wkt = (f16*)(wsb + 82182144);
  f16* wvt = (f16*)(wsb + 82477056);
  f16* wot = (f16*)(wsb + 82771968);

  // 1. fused preprocess (XCD-chunked, high-ILP dw bodies)
  preprocess<<<4104, 256, 0, stream>>>(
      inputs_q, inputs_kv,
      q_dwk, q_bs, q_bb, q_bm, q_bv,
      k_dwk, k_bs, k_bb, k_bm, k_bv,
      v_dwk, v_bs, v_bb, v_bm, v_bv,
      q_pwk, k_pwk, v_pwk, out_kern, wqt, wkt, wvt, wot,
      qdw, kdw, vdw);
  // 2. fused q/k/v pointwise GEMMs (V written transposed; q folded with 1/8*log2e)
  gemm_qkv<<<882, 256, 0, stream>>>(qdw, wqt, qf, 0.125f * LOG2E,
                                    kdw, wkt, kf, vdw, wvt, vtp);
  // 3. MFMA attention (single-buffer T14, launch_bounds(256,6)) -> f16 O
  attn_mfma<<<BB * NHD * 49, 256, 0, stream>>>(qf, kf, vtp, of);
  // 4. output projection (MFMA, fp32 out)
  gemm_mfma<0><<<dim3(196, 3), 256, 0, stream>>>(of, wot, (float*)d_out, nullptr, 1.0f);
}

// Round 21
// 140.903 us; speedup vs baseline: 1.0551x; 1.0551x over previous
//
#include <hip/hip_runtime.h>
#include <hip/hip_bf16.h>
#include <hip/hip_fp16.h>

// Problem constants
#define BB 8
#define HH 56
#define WW 56
#define CC 384
#define NHD 6
#define DD 64
#define HK 28
#define WK 28
#define NQ (HH*WW)       // 3136
#define NKV (HK*WK)      // 784
#define NTOK (BB*NQ)     // 25088
#define NTOKKV (BB*NKV)  // 6272
#define BN_EPS 1e-5f
#define LOG2E 1.44269504f

typedef _Float16 f16;
typedef _Float16 f16x2 __attribute__((ext_vector_type(2)));
typedef _Float16 f16x4 __attribute__((ext_vector_type(4)));
typedef _Float16 f16x8 __attribute__((ext_vector_type(8)));
typedef float f32x4 __attribute__((ext_vector_type(4)));

__device__ __forceinline__ float fast_exp2(float x) {
#if __has_builtin(__builtin_amdgcn_exp2f)
  return __builtin_amdgcn_exp2f(x);   // v_exp_f32 (2^x)
#else
  return __expf(x * 0.69314718056f);
#endif
}

__device__ __forceinline__ f16x4 pack4(float p0, float p1, float p2, float p3) {
#if __has_builtin(__builtin_amdgcn_cvt_pkrtz)
  f16x2 a = __builtin_bit_cast(f16x2, __builtin_amdgcn_cvt_pkrtz(p0, p1));
  f16x2 b = __builtin_bit_cast(f16x2, __builtin_amdgcn_cvt_pkrtz(p2, p3));
  return __builtin_shufflevector(a, b, 0, 1, 2, 3);
#else
  f16x4 r; r[0] = (f16)p0; r[1] = (f16)p1; r[2] = (f16)p2; r[3] = (f16)p3;
  return r;
#endif
}

// ---------------- dw conv + BN bodies (high-ILP: all loads hoisted) ----------------
// dw_s1: 2x2 output quad per thread. 16 input float4 + 9 weight float4 up-front.
__device__ __forceinline__ void dw_s1_body(
    int blk, int tid, const float* __restrict__ in, const float* __restrict__ w,
    const float* __restrict__ bns, const float* __restrict__ bnb,
    const float* __restrict__ bnm, const float* __restrict__ bnv,
    f16* __restrict__ out) {
  int idx = blk * 256 + tid;                     // < 602112 = (NTOK/4)*96
  int pp = idx / 96;
  int c = (idx % 96) * 4;
  int b = pp / 784;                              // 28*28 quads per image
  int rem = pp % 784;
  int yh = rem / 28, xh = rem % 28;
  int y0 = yh * 2, x0 = xh * 2;
  const float4 z4 = {0.f, 0.f, 0.f, 0.f};

  float4 V[4][4];
#pragma unroll
  for (int ry = 0; ry < 4; ++ry) {
    const int iy = y0 - 1 + ry;
    const bool vy = (unsigned)iy < (unsigned)HH;
    const float* rp = in + ((size_t)(b * HH + (vy ? iy : 0)) * WW) * CC + c;
    V[ry][0] = (vy && x0 > 0)      ? *(const float4*)(rp + (size_t)(x0 - 1) * CC) : z4;
    V[ry][1] = vy                  ? *(const float4*)(rp + (size_t)x0 * CC)       : z4;
    V[ry][2] = vy                  ? *(const float4*)(rp + (size_t)(x0 + 1) * CC) : z4;
    V[ry][3] = (vy && x0 < WW - 2) ? *(const float4*)(rp + (size_t)(x0 + 2) * CC) : z4;
  }
  float4 W[9];
#pragma unroll
  for (int i = 0; i < 9; ++i) W[i] = *(const float4*)(w + i * CC + c);

  const float4 s = *(const float4*)(bns + c);
  const float4 bi = *(const float4*)(bnb + c);
  const float4 m = *(const float4*)(bnm + c);
  const float4 va = *(const float4*)(bnv + c);
  const float gx = s.x * rsqrtf(va.x + BN_EPS);
  const float gy = s.y * rsqrtf(va.y + BN_EPS);
  const float gz = s.z * rsqrtf(va.z + BN_EPS);
  const float gw = s.w * rsqrtf(va.w + BN_EPS);

#pragma unroll
  for (int dy = 0; dy < 2; ++dy)
#pragma unroll
    for (int dx = 0; dx < 2; ++dx) {
      float ax = 0.f, ay = 0.f, az = 0.f, aw = 0.f;
#pragma unroll
      for (int ky = 0; ky < 3; ++ky)
#pragma unroll
        for (int kx = 0; kx < 3; ++kx) {
          const float4 v = V[dy + ky][dx + kx];
          const float4 wk = W[ky * 3 + kx];
          ax = fmaf(v.x, wk.x, ax); ay = fmaf(v.y, wk.y, ay);
          az = fmaf(v.z, wk.z, az); aw = fmaf(v.w, wk.w, aw);
        }
      f16x4 r;
      r[0] = (f16)fmaf(ax - m.x, gx, bi.x);
      r[1] = (f16)fmaf(ay - m.y, gy, bi.y);
      r[2] = (f16)fmaf(az - m.z, gz, bi.z);
      r[3] = (f16)fmaf(aw - m.w, gw, bi.w);
      const size_t pix = (size_t)b * NQ + (size_t)(y0 + dy) * WW + (x0 + dx);
      *(f16x4*)(out + pix * CC + c) = r;
    }
}

// dw_s2 (stride 2): 2 adjacent output pixels per thread; 15 input float4 shared
// between both outputs AND both (k,v) weight sets.
__device__ __forceinline__ void dw_s2_body(
    int blk, int tid, const float* __restrict__ in,
    const float* __restrict__ wk_, const float* __restrict__ kbs, const float* __restrict__ kbb,
    const float* __restrict__ kbm, const float* __restrict__ kbv,
    const float* __restrict__ wv_, const float* __restrict__ vbs, const float* __restrict__ vbb,
    const float* __restrict__ vbm, const float* __restrict__ vbv,
    f16* __restrict__ outk, f16* __restrict__ outv) {
  int idx = blk * 256 + tid;                     // < 301056 = (NTOKKV/2)*96
  int pp = idx / 96;
  int c = (idx % 96) * 4;
  int b = pp / 392;                              // 28*14 pairs per image
  int rem = pp % 392;
  int oy = rem / 14, xh = rem % 14;
  int ox0 = xh * 2;
  int iy0 = oy * 2, ix0 = ox0 * 2;
  const float4 z4 = {0.f, 0.f, 0.f, 0.f};

  float4 V[3][5];
#pragma unroll
  for (int ry = 0; ry < 3; ++ry) {
    const int iy = iy0 + ry;
    const bool vy = iy < HH;
    const float* rp = in + ((size_t)(b * HH + (vy ? iy : 0)) * WW) * CC + c;
#pragma unroll
    for (int cx = 0; cx < 5; ++cx) {
      const int ix = ix0 + cx;
      V[ry][cx] = (vy && ix < WW) ? *(const float4*)(rp + (size_t)ix * CC) : z4;
    }
  }

  // ---- k path ----
  {
    float4 W[9];
#pragma unroll
    for (int i = 0; i < 9; ++i) W[i] = *(const float4*)(wk_ + i * CC + c);
    const float4 s = *(const float4*)(kbs + c);
    const float4 bi = *(const float4*)(kbb + c);
    const float4 m = *(const float4*)(kbm + c);
    const float4 va = *(const float4*)(kbv + c);
    const float gx = s.x * rsqrtf(va.x + BN_EPS);
    const float gy = s.y * rsqrtf(va.y + BN_EPS);
    const float gz = s.z * rsqrtf(va.z + BN_EPS);
    const float gw = s.w * rsqrtf(va.w + BN_EPS);
#pragma unroll
    for (int dx = 0; dx < 2; ++dx) {
      float ax = 0.f, ay = 0.f, az = 0.f, aw = 0.f;
#pragma unroll
      for (int ky = 0; ky < 3; ++ky)
#pragma unroll
        for (int kx = 0; kx < 3; ++kx) {
          const float4 v = V[ky][2 * dx + kx];
          const float4 wk = W[ky * 3 + kx];
          ax = fmaf(v.x, wk.x, ax); ay = fmaf(v.y, wk.y, ay);
          az = fmaf(v.z, wk.z, az); aw = fmaf(v.w, wk.w, aw);
        }
      f16x4 r;
      r[0] = (f16)fmaf(ax - m.x, gx, bi.x);
      r[1] = (f16)fmaf(ay - m.y, gy, bi.y);
      r[2] = (f16)fmaf(az - m.z, gz, bi.z);
      r[3] = (f16)fmaf(aw - m.w, gw, bi.w);
      const size_t pix = (size_t)b * NKV + (size_t)oy * WK + (ox0 + dx);
      *(f16x4*)(outk + pix * CC + c) = r;
    }
  }
  // ---- v path (reuses V) ----
  {
    float4 W[9];
#pragma unroll
    for (int i = 0; i < 9; ++i) W[i] = *(const float4*)(wv_ + i * CC + c);
    const float4 s = *(const float4*)(vbs + c);
    const float4 bi = *(const float4*)(vbb + c);
    const float4 m = *(const float4*)(vbm + c);
    const float4 va = *(const float4*)(vbv + c);
    const float gx = s.x * rsqrtf(va.x + BN_EPS);
    const float gy = s.y * rsqrtf(va.y + BN_EPS);
    const float gz = s.z * rsqrtf(va.z + BN_EPS);
    const float gw = s.w * rsqrtf(va.w + BN_EPS);
#pragma unroll
    for (int dx = 0; dx < 2; ++dx) {
      float ax = 0.f, ay = 0.f, az = 0.f, aw = 0.f;
#pragma unroll
      for (int ky = 0; ky < 3; ++ky)
#pragma unroll
        for (int kx = 0; kx < 3; ++kx) {
          const float4 v = V[ky][2 * dx + kx];
          const float4 wk = W[ky * 3 + kx];
          ax = fmaf(v.x, wk.x, ax); ay = fmaf(v.y, wk.y, ay);
          az = fmaf(v.z, wk.z, az); aw = fmaf(v.w, wk.w, aw);
        }
      f16x4 r;
      r[0] = (f16)fmaf(ax - m.x, gx, bi.x);
      r[1] = (f16)fmaf(ay - m.y, gy, bi.y);
      r[2] = (f16)fmaf(az - m.z, gz, bi.z);
      r[3] = (f16)fmaf(aw - m.w, gw, bi.w);
      const size_t pix = (size_t)b * NKV + (size_t)oy * WK + (ox0 + dx);
      *(f16x4*)(outv + pix * CC + c) = r;
    }
  }
}

// ---- fused preprocess: dw_s1 (2352) + dw_s2_kv (1176) + convert_w (576) ----
// Segments XCD-chunked (contiguous image span per XCD).
__global__ __launch_bounds__(256) void preprocess(
    const float* __restrict__ inputs_q, const float* __restrict__ inputs_kv,
    const float* __restrict__ q_dwk, const float* __restrict__ q_bs,
    const float* __restrict__ q_bb, const float* __restrict__ q_bm,
    const float* __restrict__ q_bv,
    const float* __restrict__ k_dwk, const float* __restrict__ k_bs,
    const float* __restrict__ k_bb, const float* __restrict__ k_bm,
    const float* __restrict__ k_bv,
    const float* __restrict__ v_dwk, const float* __restrict__ v_bs,
    const float* __restrict__ v_bb, const float* __restrict__ v_bm,
    const float* __restrict__ v_bv,
    const float* __restrict__ w0, const float* __restrict__ w1,
    const float* __restrict__ w2, const float* __restrict__ w3,
    f16* __restrict__ o0, f16* __restrict__ o1,
    f16* __restrict__ o2, f16* __restrict__ o3,
    f16* __restrict__ qdw, f16* __restrict__ kdw, f16* __restrict__ vdw) {
  __shared__ float t[32][33];
  const int bid = blockIdx.x;
  const int tid = threadIdx.x;
  if (bid < 2352) {
    const int lb = (bid & 7) * 294 + (bid >> 3);        // 2352 = 8*294, bijective
    dw_s1_body(lb, tid, inputs_q, q_dwk, q_bs, q_bb, q_bm, q_bv, qdw);
  } else if (bid < 3528) {
    const int r = bid - 2352;                           // 1176 = 8*147
    const int lb = (r & 7) * 147 + (r >> 3);
    dw_s2_body(lb, tid, inputs_kv,
               k_dwk, k_bs, k_bb, k_bm, k_bv,
               v_dwk, v_bs, v_bb, v_bm, v_bv, kdw, vdw);
  } else {
    const int r = bid - 3528;                 // 0..575  (12 x 12 x 4)
    const int z = r / 144, rem = r % 144;
    const int bx = rem % 12, by = rem / 12;
    const float* src = z == 0 ? w0 : z == 1 ? w1 : z == 2 ? w2 : w3;
    f16* dst = z == 0 ? o0 : z == 1 ? o1 : z == 2 ? o2 : o3;
    const int k0 = bx * 32, n0 = by * 32;
    const int x = tid & 31, y = tid >> 5;
#pragma unroll
    for (int i = 0; i < 4; ++i) t[y + i * 8][x] = src[(size_t)(k0 + y + i * 8) * 384 + n0 + x];
    __syncthreads();
#pragma unroll
    for (int i = 0; i < 4; ++i)
      dst[(size_t)(n0 + y + i * 8) * 384 + k0 + x] = (f16)t[x][y + i * 8];
  }
}

// ------------- f16 MFMA GEMM body (128x128 tile, BK=64, 4 waves, 4x4 frags) -------------
// MODE 0: fp32 row-major; MODE 1: f16 row-major; MODE 2: f16 V^T (vtp [b*384+d][784])
template <int MODE>
__device__ __forceinline__ void gemm_body(
    const f16* __restrict__ A, const f16* __restrict__ Bt,
    float* __restrict__ Cf, f16* __restrict__ Ch, float scale,
    int row0, int col0) {
  __shared__ f16 As[128 * 64];   // [row][k], 128 B per row
  __shared__ f16 Bs[128 * 64];   // [col][k], 128 B per col
  const int tid = threadIdx.x;
  const int wave = tid >> 6, lane = tid & 63;
  const int c = lane & 15, g = lane >> 4;
  const int wr = wave >> 1, wc = wave & 1;     // 2x2 waves, each 64x64

  const int s_base = wave * 64 + lane;
  f32x4 acc[4][4] = {};

  for (int k0 = 0; k0 < 384; k0 += 64) {
    __syncthreads();
#pragma unroll
    for (int j = 0; j < 4; ++j) {
      const int s = j * 256 + s_base;
      const int row = s >> 3, sch = s & 7;
      const int lch = sch ^ (row & 7);         // logical k-chunk fetched
      const f16* sa = A + (size_t)(row0 + row) * 384 + k0 + lch * 8;
      __builtin_amdgcn_global_load_lds(
          (const __attribute__((address_space(1))) void*)sa,
          (__attribute__((address_space(3))) void*)(As + j * 2048 + wave * 512), 16, 0, 0);
      const f16* sb = Bt + (size_t)(col0 + row) * 384 + k0 + lch * 8;
      __builtin_amdgcn_global_load_lds(
          (const __attribute__((address_space(1))) void*)sb,
          (__attribute__((address_space(3))) void*)(Bs + j * 2048 + wave * 512), 16, 0, 0);
    }
    __syncthreads();

#pragma unroll
    for (int kh = 0; kh < 2; ++kh) {
      f16x8 bf[4];
#pragma unroll
      for (int n = 0; n < 4; ++n) {
        const int row = wc * 64 + n * 16 + c;
        bf[n] = *(const f16x8*)(Bs + (size_t)row * 64 + ((kh * 4 + g) ^ (row & 7)) * 8);
      }
#pragma unroll
      for (int m = 0; m < 4; ++m) {
        const int row = wr * 64 + m * 16 + c;
        f16x8 af = *(const f16x8*)(As + (size_t)row * 64 + ((kh * 4 + g) ^ (row & 7)) * 8);
#pragma unroll
        for (int n = 0; n < 4; ++n)
          acc[m][n] = __builtin_amdgcn_mfma_f32_16x16x32_f16(af, bf[n], acc[m][n], 0, 0, 0);
      }
    }
  }

  if (MODE == 2) {
#pragma unroll
    for (int m = 0; m < 4; ++m)
#pragma unroll
      for (int n = 0; n < 4; ++n) {
        const int gr = row0 + wr * 64 + m * 16 + g * 4;
        const int col = col0 + wc * 64 + n * 16 + c;
        const int bb = gr / NKV;
        const int kv = gr - bb * NKV;           // 4-pack cannot cross batch (784%4==0, gr%4==0)
        f16x4 pk;
#pragma unroll
        for (int r = 0; r < 4; ++r) pk[r] = (f16)(acc[m][n][r] * scale);
        *(f16x4*)(Ch + ((size_t)bb * 384 + col) * NKV + kv) = pk;
      }
  } else {
#pragma unroll
    for (int m = 0; m < 4; ++m)
#pragma unroll
      for (int n = 0; n < 4; ++n)
#pragma unroll
        for (int r = 0; r < 4; ++r) {
          const size_t row = row0 + wr * 64 + m * 16 + g * 4 + r;
          const size_t col = col0 + wc * 64 + n * 16 + c;
          if (MODE == 1) Ch[row * 384 + col] = (f16)(acc[m][n][r] * scale);
          else           Cf[row * 384 + col] = acc[m][n][r] * scale;
        }
  }
}

// fused q/k/v pointwise GEMMs: 882 flat blocks = q(196x3) + k(49x3) + v(49x3)
__global__ __launch_bounds__(256) void gemm_qkv(
    const f16* __restrict__ qdw, const f16* __restrict__ wqt, f16* __restrict__ qf, float qscale,
    const f16* __restrict__ kdw, const f16* __restrict__ wkt, f16* __restrict__ kf,
    const f16* __restrict__ vdw, const f16* __restrict__ wvt, f16* __restrict__ vtp) {
  const int blk = blockIdx.x;
  if (blk < 588) {
    gemm_body<1>(qdw, wqt, nullptr, qf, qscale, (blk % 196) * 128, (blk / 196) * 128);
  } else if (blk < 735) {
    const int r = blk - 588;
    gemm_body<1>(kdw, wkt, nullptr, kf, 1.0f, (r % 49) * 128, (r / 49) * 128);
  } else {
    const int r = blk - 735;
    gemm_body<2>(vdw, wvt, nullptr, vtp, 1.0f, (r % 49) * 128, (r / 49) * 128);
  }
}

template <int MODE>
__global__ __launch_bounds__(256) void gemm_mfma(
    const f16* __restrict__ A, const f16* __restrict__ Bt,
    float* __restrict__ Cf, f16* __restrict__ Ch, float scale) {
  gemm_body<MODE>(A, Bt, Cf, Ch, scale, blockIdx.x * 128, blockIdx.y * 128);
}

// ------------- f16 MFMA flash attention: software-pipelined S, dbuf, T14 -------------
// grid = 2352; lb = (bid&7)*294 + (bid>>3): each XCD owns 6 complete (b,h) pairs.
// Iter t: {write regs->buf[nxt] (K/V t+1); issue loads(t+2)->regs; softmax(t) on
// register S; barrier A; PV(t) from buf[cur] + S(t+1) from buf[nxt] (independent
// MFMA streams); barrier B}. Softmax is off the MFMA critical path.
// Buffer safety: buf[cur] last read at PV(t) (before barrier B); iter t+1 writes
// buf[cur] only after barrier B. buf[nxt] written before barrier A, read after. All
// __syncthreads -- no raw-barrier hazards. Ops identical to R18 -> bitwise output.
__global__ __launch_bounds__(256) void attn_mfma(
    const f16* __restrict__ qp, const f16* __restrict__ kp,
    const f16* __restrict__ vt, f16* __restrict__ op) {
  __shared__ f16 Ks[2][64 * 64];   // [buf][kv][d], chunk ch at ch^(kv&7)
  __shared__ f16 Vs[2][64 * 64];   // [buf][d][kv], chunk ch at ch^(d&7)
  __shared__ f16 Ps[4][16 * 64];   // per-wave [q][kv], ch^(q&7)
  const int bid0 = blockIdx.x;
  const int lb = (bid0 & 7) * 294 + (bid0 >> 3);   // bijective (2352 = 8*294)
  const int qt = lb % 49;
  const int bh = lb / 49;
  const int h = bh % NHD, b = bh / NHD;
  const int tid = threadIdx.x;
  const int wave = tid >> 6, lane = tid & 63;
  const int c = lane & 15, g = lane >> 4;

  const size_t qrow = (size_t)b * NQ + qt * 64 + wave * 16 + c;
  f16x8 qa[2];
  qa[0] = *(const f16x8*)(qp + qrow * 384 + h * 64 + g * 8);
  qa[1] = *(const f16x8*)(qp + qrow * 384 + h * 64 + 32 + g * 8);

  f16x8 vones;
#pragma unroll
  for (int j = 0; j < 8; ++j) vones[j] = (f16)1.0f;

  const int tid8 = tid >> 3, tch = tid & 7;
  const int lch = tch ^ (tid8 & 7);            // logical chunk fetched

  const f16* kbase = kp + ((size_t)b * NKV) * 384 + h * 64;
  const f16* vbase = vt + ((size_t)(b * 384 + h * 64)) * NKV;

  float mrun = -1e30f;                // for q = c (redundant across g)
  f32x4 o[4] = {};                    // O[q=g*4+r][d=dt*16+c]
  f32x4 osum = {};                    // lsum[q=g*4+r]
  f16* prow = &Ps[wave][0];

  // ---- prologue: tile 0 -> buf0; issue tile 1 loads; compute S(0) ----
  f16x8 kr0, kr1, vr0, vr1;
  kr0 = *(const f16x8*)(kbase + (size_t)tid8 * 384 + lch * 8);
  kr1 = *(const f16x8*)(kbase + (size_t)(32 + tid8) * 384 + lch * 8);
  vr0 = *(const f16x8*)(vbase + (size_t)tid8 * NKV + lch * 8);
  vr1 = *(const f16x8*)(vbase + (size_t)(32 + tid8) * NKV + lch * 8);
  *(f16x8*)(&Ks[0][0] + tid * 8) = kr0;
  *(f16x8*)(&Ks[0][0] + 2048 + tid * 8) = kr1;
  *(f16x8*)(&Vs[0][0] + tid * 8) = vr0;
  *(f16x8*)(&Vs[0][0] + 2048 + tid * 8) = vr1;
  kr0 = *(const f16x8*)(kbase + (size_t)(64 + tid8) * 384 + lch * 8);
  kr1 = *(const f16x8*)(kbase + (size_t)(96 + tid8) * 384 + lch * 8);
  vr0 = *(const f16x8*)(vbase + (size_t)tid8 * NKV + 64 + lch * 8);
  vr1 = *(const f16x8*)(vbase + (size_t)(32 + tid8) * NKV + 64 + lch * 8);
  __syncthreads();

  f32x4 scur[4] = {};
  __builtin_amdgcn_s_setprio(1);
#pragma unroll
  for (int kh = 0; kh < 2; ++kh) {
#pragma unroll
    for (int ct = 0; ct < 4; ++ct) {
      const int row = ct * 16 + c;
      const int sch = (kh * 4 + g) ^ (row & 7);
      f16x8 kb = *(const f16x8*)(&Ks[0][0] + row * 64 + sch * 8);
      scur[ct] = __builtin_amdgcn_mfma_f32_16x16x32_f16(kb, qa[kh], scur[ct], 0, 0, 0);
    }
  }
  __builtin_amdgcn_s_setprio(0);

  int cur = 0;
  for (int ti = 0; ti < 13; ++ti) {
    const int nxt = cur ^ 1;
    // 1. write staged K/V(ti+1) -> buf[nxt] (last read protected by barrier B of ti-1)
    if (ti + 1 < 13) {
      f16* ksw = &Ks[nxt][0];
      f16* vsw = &Vs[nxt][0];
      *(f16x8*)(ksw + tid * 8) = kr0;
      *(f16x8*)(ksw + 2048 + tid * 8) = kr1;
      *(f16x8*)(vsw + tid * 8) = vr0;
      *(f16x8*)(vsw + 2048 + tid * 8) = vr1;
    }
    // 2. issue loads for tile ti+2 (fly across this iteration)
    if (ti + 2 < 13) {
      const int t0n = (ti + 2) * 64;
      int kvA = t0n + tid8;        if (kvA > NKV - 1) kvA = NKV - 1;
      int kvB = t0n + 32 + tid8;   if (kvB > NKV - 1) kvB = NKV - 1;
      int colc = t0n + lch * 8;    if (colc > NKV - 8) colc = NKV - 8;
      kr0 = *(const f16x8*)(kbase + (size_t)kvA * 384 + lch * 8);
      kr1 = *(const f16x8*)(kbase + (size_t)kvB * 384 + lch * 8);
      vr0 = *(const f16x8*)(vbase + (size_t)tid8 * NKV + colc);
      vr1 = *(const f16x8*)(vbase + (size_t)(32 + tid8) * NKV + colc);
    }
    // 3. softmax(ti) on register S (VALU-only; off the MFMA critical path)
    if (ti < 12) {
      float mt = scur[0][0];
#pragma unroll
      for (int ct = 0; ct < 4; ++ct)
#pragma unroll
        for (int r = 0; r < 4; ++r) mt = fmaxf(mt, scur[ct][r]);
      mt = fmaxf(mt, __shfl_xor(mt, 16));
      mt = fmaxf(mt, __shfl_xor(mt, 32));
      if (__ballot(mt > mrun + 8.0f)) {   // defer-max: P bounded by 2^8
        const float mnew = fmaxf(mrun, mt);
        const float corr = fast_exp2(mrun - mnew);
        mrun = mnew;
#pragma unroll
        for (int r = 0; r < 4; ++r) {
          const float co = __shfl(corr, g * 4 + r);
#pragma unroll
          for (int dt = 0; dt < 4; ++dt) o[dt][r] *= co;
          osum[r] *= co;
        }
      }
#pragma unroll
      for (int ct = 0; ct < 4; ++ct) {
        const float p0 = fast_exp2(scur[ct][0] - mrun);
        const float p1 = fast_exp2(scur[ct][1] - mrun);
        const float p2 = fast_exp2(scur[ct][2] - mrun);
        const float p3 = fast_exp2(scur[ct][3] - mrun);
        const int sch = (ct * 2 + (g >> 1)) ^ (c & 7);
        *(f16x4*)(prow + c * 64 + sch * 8 + (g & 1) * 4) = pack4(p0, p1, p2, p3);
      }
    } else {
      // tail tile (t0=768): only scur[0] (kv 768+c) is valid
      float mt = fmaxf(fmaxf(scur[0][0], scur[0][1]), fmaxf(scur[0][2], scur[0][3]));
      mt = fmaxf(mt, __shfl_xor(mt, 16));
      mt = fmaxf(mt, __shfl_xor(mt, 32));
      if (__ballot(mt > mrun + 8.0f)) {
        const float mnew = fmaxf(mrun, mt);
        const float corr = fast_exp2(mrun - mnew);
        mrun = mnew;
#pragma unroll
        for (int r = 0; r < 4; ++r) {
          const float co = __shfl(corr, g * 4 + r);
#pragma unroll
          for (int dt = 0; dt < 4; ++dt) o[dt][r] *= co;
          osum[r] *= co;
        }
      }
      const float p0 = fast_exp2(scur[0][0] - mrun);
      const float p1 = fast_exp2(scur[0][1] - mrun);
      const float p2 = fast_exp2(scur[0][2] - mrun);
      const float p3 = fast_exp2(scur[0][3] - mrun);
      const int sch0 = (0 + (g >> 1)) ^ (c & 7);
      *(f16x4*)(prow + c * 64 + sch0 * 8 + (g & 1) * 4) = pack4(p0, p1, p2, p3);
      const int sch1 = (2 + (g >> 1)) ^ (c & 7);
      f16x4 z = {};
      *(f16x4*)(prow + c * 64 + sch1 * 8 + (g & 1) * 4) = z;
    }
    __syncthreads();                  // barrier A: buf[nxt] visible
    const f16* vsb = &Vs[cur][0];
    const f16* ksb = &Ks[nxt][0];

    // 4. PV(ti) from buf[cur] + 5. S(ti+1) from buf[nxt] -- independent MFMA streams
    __builtin_amdgcn_s_setprio(1);
    if (ti < 12) {
#pragma unroll
      for (int ks = 0; ks < 2; ++ks) {
        const int sp = (ks * 4 + g) ^ (c & 7);
        f16x8 pa = *(const f16x8*)(prow + c * 64 + sp * 8);
#pragma unroll
        for (int dt = 0; dt < 4; ++dt) {
          const int d = dt * 16 + c;
          f16x8 vb = *(const f16x8*)(vsb + d * 64 + sp * 8);
          o[dt] = __builtin_amdgcn_mfma_f32_16x16x32_f16(pa, vb, o[dt], 0, 0, 0);
        }
        osum = __builtin_amdgcn_mfma_f32_16x16x32_f16(pa, vones, osum, 0, 0, 0);
      }
    } else {
      const int sp = g ^ (c & 7);
      f16x8 pa = *(const f16x8*)(prow + c * 64 + sp * 8);
#pragma unroll
      for (int dt = 0; dt < 4; ++dt) {
        const int d = dt * 16 + c;
        f16x8 vb = *(const f16x8*)(vsb + d * 64 + sp * 8);
        o[dt] = __builtin_amdgcn_mfma_f32_16x16x32_f16(pa, vb, o[dt], 0, 0, 0);
      }
      osum = __builtin_amdgcn_mfma_f32_16x16x32_f16(pa, vones, osum, 0, 0, 0);
    }

    f32x4 snext[4] = {};
    if (ti + 1 < 12) {
#pragma unroll
      for (int kh = 0; kh < 2; ++kh) {
#pragma unroll
        for (int ct = 0; ct < 4; ++ct) {
          const int row = ct * 16 + c;
          const int sch = (kh * 4 + g) ^ (row & 7);
          f16x8 kb = *(const f16x8*)(ksb + row * 64 + sch * 8);
          snext[ct] = __builtin_amdgcn_mfma_f32_16x16x32_f16(kb, qa[kh], snext[ct], 0, 0, 0);
        }
      }
    } else if (ti + 1 == 12) {
#pragma unroll
      for (int kh = 0; kh < 2; ++kh) {
        const int sch = (kh * 4 + g) ^ (c & 7);
        f16x8 kb = *(const f16x8*)(ksb + c * 64 + sch * 8);
        snext[0] = __builtin_amdgcn_mfma_f32_16x16x32_f16(kb, qa[kh], snext[0], 0, 0, 0);
      }
    }
    __builtin_amdgcn_s_setprio(0);
    __syncthreads();                  // barrier B: buf[cur] reads done before next write
#pragma unroll
    for (int i = 0; i < 4; ++i) scur[i] = snext[i];
    cur = nxt;
  }

  // epilogue: osum already in q=g*4+r row layout -> no shuffles
  f16* obase = op + ((size_t)(b * NQ + qt * 64 + wave * 16)) * 384 + h * 64;
#pragma unroll
  for (int r = 0; r < 4; ++r) {
    const float iv = 1.0f / osum[r];
#pragma unroll
    for (int dt = 0; dt < 4; ++dt)
      obase[(size_t)(g * 4 + r) * 384 + dt * 16 + c] = (f16)(o[dt][r] * iv);
  }
}

extern "C" void kernel_launch(void* const* d_in, const int* in_sizes, int n_in,
                              void* d_out, int out_size, void* d_ws, size_t ws_size,
                              hipStream_t stream) {
  const float* inputs_q  = (const float*)d_in[0];
  const float* inputs_kv = (const float*)d_in[1];
  const float* out_kern  = (const float*)d_in[2];
  const float* q_dwk = (const float*)d_in[3];
  const float* q_bs  = (const float*)d_in[4];
  const float* q_bb  = (const float*)d_in[5];
  const float* q_bm  = (const float*)d_in[6];
  const float* q_bv  = (const float*)d_in[7];
  const float* q_pwk = (const float*)d_in[8];
  const float* k_dwk = (const float*)d_in[9];
  const float* k_bs  = (const float*)d_in[10];
  const float* k_bb  = (const float*)d_in[11];
  const float* k_bm  = (const float*)d_in[12];
  const float* k_bv  = (const float*)d_in[13];
  const float* k_pwk = (const float*)d_in[14];
  const float* v_dwk = (const float*)d_in[15];
  const float* v_bs  = (const float*)d_in[16];
  const float* v_bb  = (const float*)d_in[17];
  const float* v_bm  = (const float*)d_in[18];
  const float* v_bv  = (const float*)d_in[19];
  const float* v_pwk = (const float*)d_in[20];

  char* wsb = (char*)d_ws;
  f16* qdw = (f16*)(wsb + 0);             // 25088*384 f16
  f16* kdw = (f16*)(wsb + 19267584);      // 6272*384 f16
  f16* vdw = (f16*)(wsb + 24084480);      // 6272*384 f16
  f16* qf  = (f16*)(wsb + 28901376);      // 25088*384 f16
  f16* kf  = (f16*)(wsb + 48168960);      // 6272*384 f16
  f16* vtp = (f16*)(wsb + 57802752);      // 8*384*784 f16
  f16* of  = (f16*)(wsb + 62619648);      // 25088*384 f16
  f16* wqt = (f16*)(wsb + 81887232);      // 384*384 f16 x4
  f16* wkt = (f16*)(wsb + 82182144);
  f16* wvt = (f16*)(wsb + 82477056);
  f16* wot = (f16*)(wsb + 82771968);

  // 1. fused preprocess (XCD-chunked, high-ILP dw bodies)
  preprocess<<<4104, 256, 0, stream>>>(
      inputs_q, inputs_kv,
      q_dwk, q_bs, q_bb, q_bm, q_bv,
      k_dwk, k_bs, k_bb, k_bm, k_bv,
      v_dwk, v_bs, v_bb, v_bm, v_bv,
      q_pwk, k_pwk, v_pwk, out_kern, wqt, wkt, wvt, wot,
      qdw, kdw, vdw);
  // 2. fused q/k/v pointwise GEMMs (V written transposed; q folded with 1/8*log2e)
  gemm_qkv<<<882, 256, 0, stream>>>(qdw, wqt, qf, 0.125f * LOG2E,
                                    kdw, wkt, kf, vdw, wvt, vtp);
  // 3. MFMA attention (software-pipelined S, dbuf, T14) -> f16 O
  attn_mfma<<<BB * NHD * 49, 256, 0, stream>>>(qf, kf, vtp, of);
  // 4. output projection (MFMA, fp32 out)
  gemm_mfma<0><<<dim3(196, 3), 256, 0, stream>>>(of, wot, (float*)d_out, nullptr, 1.0f);
}

// Round 22
// 137.812 us; speedup vs baseline: 1.0787x; 1.0224x over previous
//
#include <hip/hip_runtime.h>
#include <hip/hip_bf16.h>
#include <hip/hip_fp16.h>

// Problem constants
#define BB 8
#define HH 56
#define WW 56
#define CC 384
#define NHD 6
#define DD 64
#define HK 28
#define WK 28
#define NQ (HH*WW)       // 3136
#define NKV (HK*WK)      // 784
#define NTOK (BB*NQ)     // 25088
#define NTOKKV (BB*NKV)  // 6272
#define BN_EPS 1e-5f
#define LOG2E 1.44269504f

typedef _Float16 f16;
typedef _Float16 f16x2 __attribute__((ext_vector_type(2)));
typedef _Float16 f16x4 __attribute__((ext_vector_type(4)));
typedef _Float16 f16x8 __attribute__((ext_vector_type(8)));
typedef float f32x4 __attribute__((ext_vector_type(4)));

__device__ __forceinline__ float fast_exp2(float x) {
#if __has_builtin(__builtin_amdgcn_exp2f)
  return __builtin_amdgcn_exp2f(x);   // v_exp_f32 (2^x)
#else
  return __expf(x * 0.69314718056f);
#endif
}

__device__ __forceinline__ f16x4 pack4(float p0, float p1, float p2, float p3) {
#if __has_builtin(__builtin_amdgcn_cvt_pkrtz)
  f16x2 a = __builtin_bit_cast(f16x2, __builtin_amdgcn_cvt_pkrtz(p0, p1));
  f16x2 b = __builtin_bit_cast(f16x2, __builtin_amdgcn_cvt_pkrtz(p2, p3));
  return __builtin_shufflevector(a, b, 0, 1, 2, 3);
#else
  f16x4 r; r[0] = (f16)p0; r[1] = (f16)p1; r[2] = (f16)p2; r[3] = (f16)p3;
  return r;
#endif
}

// ---------------- dw conv + BN bodies (high-ILP: all loads hoisted) ----------------
// dw_s1: 2x2 output quad per thread. 16 input float4 + 9 weight float4 up-front.
__device__ __forceinline__ void dw_s1_body(
    int blk, int tid, const float* __restrict__ in, const float* __restrict__ w,
    const float* __restrict__ bns, const float* __restrict__ bnb,
    const float* __restrict__ bnm, const float* __restrict__ bnv,
    f16* __restrict__ out) {
  int idx = blk * 256 + tid;                     // < 602112 = (NTOK/4)*96
  int pp = idx / 96;
  int c = (idx % 96) * 4;
  int b = pp / 784;                              // 28*28 quads per image
  int rem = pp % 784;
  int yh = rem / 28, xh = rem % 28;
  int y0 = yh * 2, x0 = xh * 2;
  const float4 z4 = {0.f, 0.f, 0.f, 0.f};

  float4 V[4][4];
#pragma unroll
  for (int ry = 0; ry < 4; ++ry) {
    const int iy = y0 - 1 + ry;
    const bool vy = (unsigned)iy < (unsigned)HH;
    const float* rp = in + ((size_t)(b * HH + (vy ? iy : 0)) * WW) * CC + c;
    V[ry][0] = (vy && x0 > 0)      ? *(const float4*)(rp + (size_t)(x0 - 1) * CC) : z4;
    V[ry][1] = vy                  ? *(const float4*)(rp + (size_t)x0 * CC)       : z4;
    V[ry][2] = vy                  ? *(const float4*)(rp + (size_t)(x0 + 1) * CC) : z4;
    V[ry][3] = (vy && x0 < WW - 2) ? *(const float4*)(rp + (size_t)(x0 + 2) * CC) : z4;
  }
  float4 W[9];
#pragma unroll
  for (int i = 0; i < 9; ++i) W[i] = *(const float4*)(w + i * CC + c);

  const float4 s = *(const float4*)(bns + c);
  const float4 bi = *(const float4*)(bnb + c);
  const float4 m = *(const float4*)(bnm + c);
  const float4 va = *(const float4*)(bnv + c);
  const float gx = s.x * rsqrtf(va.x + BN_EPS);
  const float gy = s.y * rsqrtf(va.y + BN_EPS);
  const float gz = s.z * rsqrtf(va.z + BN_EPS);
  const float gw = s.w * rsqrtf(va.w + BN_EPS);

#pragma unroll
  for (int dy = 0; dy < 2; ++dy)
#pragma unroll
    for (int dx = 0; dx < 2; ++dx) {
      float ax = 0.f, ay = 0.f, az = 0.f, aw = 0.f;
#pragma unroll
      for (int ky = 0; ky < 3; ++ky)
#pragma unroll
        for (int kx = 0; kx < 3; ++kx) {
          const float4 v = V[dy + ky][dx + kx];
          const float4 wk = W[ky * 3 + kx];
          ax = fmaf(v.x, wk.x, ax); ay = fmaf(v.y, wk.y, ay);
          az = fmaf(v.z, wk.z, az); aw = fmaf(v.w, wk.w, aw);
        }
      f16x4 r;
      r[0] = (f16)fmaf(ax - m.x, gx, bi.x);
      r[1] = (f16)fmaf(ay - m.y, gy, bi.y);
      r[2] = (f16)fmaf(az - m.z, gz, bi.z);
      r[3] = (f16)fmaf(aw - m.w, gw, bi.w);
      const size_t pix = (size_t)b * NQ + (size_t)(y0 + dy) * WW + (x0 + dx);
      *(f16x4*)(out + pix * CC + c) = r;
    }
}

// dw_s2 (stride 2): 2 adjacent output pixels per thread; 15 input float4 shared
// between both outputs AND both (k,v) weight sets.
__device__ __forceinline__ void dw_s2_body(
    int blk, int tid, const float* __restrict__ in,
    const float* __restrict__ wk_, const float* __restrict__ kbs, const float* __restrict__ kbb,
    const float* __restrict__ kbm, const float* __restrict__ kbv,
    const float* __restrict__ wv_, const float* __restrict__ vbs, const float* __restrict__ vbb,
    const float* __restrict__ vbm, const float* __restrict__ vbv,
    f16* __restrict__ outk, f16* __restrict__ outv) {
  int idx = blk * 256 + tid;                     // < 301056 = (NTOKKV/2)*96
  int pp = idx / 96;
  int c = (idx % 96) * 4;
  int b = pp / 392;                              // 28*14 pairs per image
  int rem = pp % 392;
  int oy = rem / 14, xh = rem % 14;
  int ox0 = xh * 2;
  int iy0 = oy * 2, ix0 = ox0 * 2;
  const float4 z4 = {0.f, 0.f, 0.f, 0.f};

  float4 V[3][5];
#pragma unroll
  for (int ry = 0; ry < 3; ++ry) {
    const int iy = iy0 + ry;
    const bool vy = iy < HH;
    const float* rp = in + ((size_t)(b * HH + (vy ? iy : 0)) * WW) * CC + c;
#pragma unroll
    for (int cx = 0; cx < 5; ++cx) {
      const int ix = ix0 + cx;
      V[ry][cx] = (vy && ix < WW) ? *(const float4*)(rp + (size_t)ix * CC) : z4;
    }
  }

  // ---- k path ----
  {
    float4 W[9];
#pragma unroll
    for (int i = 0; i < 9; ++i) W[i] = *(const float4*)(wk_ + i * CC + c);
    const float4 s = *(const float4*)(kbs + c);
    const float4 bi = *(const float4*)(kbb + c);
    const float4 m = *(const float4*)(kbm + c);
    const float4 va = *(const float4*)(kbv + c);
    const float gx = s.x * rsqrtf(va.x + BN_EPS);
    const float gy = s.y * rsqrtf(va.y + BN_EPS);
    const float gz = s.z * rsqrtf(va.z + BN_EPS);
    const float gw = s.w * rsqrtf(va.w + BN_EPS);
#pragma unroll
    for (int dx = 0; dx < 2; ++dx) {
      float ax = 0.f, ay = 0.f, az = 0.f, aw = 0.f;
#pragma unroll
      for (int ky = 0; ky < 3; ++ky)
#pragma unroll
        for (int kx = 0; kx < 3; ++kx) {
          const float4 v = V[ky][2 * dx + kx];
          const float4 wk = W[ky * 3 + kx];
          ax = fmaf(v.x, wk.x, ax); ay = fmaf(v.y, wk.y, ay);
          az = fmaf(v.z, wk.z, az); aw = fmaf(v.w, wk.w, aw);
        }
      f16x4 r;
      r[0] = (f16)fmaf(ax - m.x, gx, bi.x);
      r[1] = (f16)fmaf(ay - m.y, gy, bi.y);
      r[2] = (f16)fmaf(az - m.z, gz, bi.z);
      r[3] = (f16)fmaf(aw - m.w, gw, bi.w);
      const size_t pix = (size_t)b * NKV + (size_t)oy * WK + (ox0 + dx);
      *(f16x4*)(outk + pix * CC + c) = r;
    }
  }
  // ---- v path (reuses V) ----
  {
    float4 W[9];
#pragma unroll
    for (int i = 0; i < 9; ++i) W[i] = *(const float4*)(wv_ + i * CC + c);
    const float4 s = *(const float4*)(vbs + c);
    const float4 bi = *(const float4*)(vbb + c);
    const float4 m = *(const float4*)(vbm + c);
    const float4 va = *(const float4*)(vbv + c);
    const float gx = s.x * rsqrtf(va.x + BN_EPS);
    const float gy = s.y * rsqrtf(va.y + BN_EPS);
    const float gz = s.z * rsqrtf(va.z + BN_EPS);
    const float gw = s.w * rsqrtf(va.w + BN_EPS);
#pragma unroll
    for (int dx = 0; dx < 2; ++dx) {
      float ax = 0.f, ay = 0.f, az = 0.f, aw = 0.f;
#pragma unroll
      for (int ky = 0; ky < 3; ++ky)
#pragma unroll
        for (int kx = 0; kx < 3; ++kx) {
          const float4 v = V[ky][2 * dx + kx];
          const float4 wk = W[ky * 3 + kx];
          ax = fmaf(v.x, wk.x, ax); ay = fmaf(v.y, wk.y, ay);
          az = fmaf(v.z, wk.z, az); aw = fmaf(v.w, wk.w, aw);
        }
      f16x4 r;
      r[0] = (f16)fmaf(ax - m.x, gx, bi.x);
      r[1] = (f16)fmaf(ay - m.y, gy, bi.y);
      r[2] = (f16)fmaf(az - m.z, gz, bi.z);
      r[3] = (f16)fmaf(aw - m.w, gw, bi.w);
      const size_t pix = (size_t)b * NKV + (size_t)oy * WK + (ox0 + dx);
      *(f16x4*)(outv + pix * CC + c) = r;
    }
  }
}

// ---- fused preprocess: dw_s1 (2352) + dw_s2_kv (1176) + convert_w (576) ----
// Segments XCD-chunked (contiguous image span per XCD).
__global__ __launch_bounds__(256) void preprocess(
    const float* __restrict__ inputs_q, const float* __restrict__ inputs_kv,
    const float* __restrict__ q_dwk, const float* __restrict__ q_bs,
    const float* __restrict__ q_bb, const float* __restrict__ q_bm,
    const float* __restrict__ q_bv,
    const float* __restrict__ k_dwk, const float* __restrict__ k_bs,
    const float* __restrict__ k_bb, const float* __restrict__ k_bm,
    const float* __restrict__ k_bv,
    const float* __restrict__ v_dwk, const float* __restrict__ v_bs,
    const float* __restrict__ v_bb, const float* __restrict__ v_bm,
    const float* __restrict__ v_bv,
    const float* __restrict__ w0, const float* __restrict__ w1,
    const float* __restrict__ w2, const float* __restrict__ w3,
    f16* __restrict__ o0, f16* __restrict__ o1,
    f16* __restrict__ o2, f16* __restrict__ o3,
    f16* __restrict__ qdw, f16* __restrict__ kdw, f16* __restrict__ vdw) {
  __shared__ float t[32][33];
  const int bid = blockIdx.x;
  const int tid = threadIdx.x;
  if (bid < 2352) {
    const int lb = (bid & 7) * 294 + (bid >> 3);        // 2352 = 8*294, bijective
    dw_s1_body(lb, tid, inputs_q, q_dwk, q_bs, q_bb, q_bm, q_bv, qdw);
  } else if (bid < 3528) {
    const int r = bid - 2352;                           // 1176 = 8*147
    const int lb = (r & 7) * 147 + (r >> 3);
    dw_s2_body(lb, tid, inputs_kv,
               k_dwk, k_bs, k_bb, k_bm, k_bv,
               v_dwk, v_bs, v_bb, v_bm, v_bv, kdw, vdw);
  } else {
    const int r = bid - 3528;                 // 0..575  (12 x 12 x 4)
    const int z = r / 144, rem = r % 144;
    const int bx = rem % 12, by = rem / 12;
    const float* src = z == 0 ? w0 : z == 1 ? w1 : z == 2 ? w2 : w3;
    f16* dst = z == 0 ? o0 : z == 1 ? o1 : z == 2 ? o2 : o3;
    const int k0 = bx * 32, n0 = by * 32;
    const int x = tid & 31, y = tid >> 5;
#pragma unroll
    for (int i = 0; i < 4; ++i) t[y + i * 8][x] = src[(size_t)(k0 + y + i * 8) * 384 + n0 + x];
    __syncthreads();
#pragma unroll
    for (int i = 0; i < 4; ++i)
      dst[(size_t)(n0 + y + i * 8) * 384 + k0 + x] = (f16)t[x][y + i * 8];
  }
}

// ------------- f16 MFMA GEMM body (128x128 tile, BK=64, 4 waves, 4x4 frags) -------------
// MODE 0: fp32 row-major; MODE 1: f16 row-major; MODE 2: f16 V^T (vtp [b*384+d][784])
template <int MODE>
__device__ __forceinline__ void gemm_body(
    const f16* __restrict__ A, const f16* __restrict__ Bt,
    float* __restrict__ Cf, f16* __restrict__ Ch, float scale,
    int row0, int col0) {
  __shared__ f16 As[128 * 64];   // [row][k], 128 B per row
  __shared__ f16 Bs[128 * 64];   // [col][k], 128 B per col
  const int tid = threadIdx.x;
  const int wave = tid >> 6, lane = tid & 63;
  const int c = lane & 15, g = lane >> 4;
  const int wr = wave >> 1, wc = wave & 1;     // 2x2 waves, each 64x64

  const int s_base = wave * 64 + lane;
  f32x4 acc[4][4] = {};

  for (int k0 = 0; k0 < 384; k0 += 64) {
    __syncthreads();
#pragma unroll
    for (int j = 0; j < 4; ++j) {
      const int s = j * 256 + s_base;
      const int row = s >> 3, sch = s & 7;
      const int lch = sch ^ (row & 7);         // logical k-chunk fetched
      const f16* sa = A + (size_t)(row0 + row) * 384 + k0 + lch * 8;
      __builtin_amdgcn_global_load_lds(
          (const __attribute__((address_space(1))) void*)sa,
          (__attribute__((address_space(3))) void*)(As + j * 2048 + wave * 512), 16, 0, 0);
      const f16* sb = Bt + (size_t)(col0 + row) * 384 + k0 + lch * 8;
      __builtin_amdgcn_global_load_lds(
          (const __attribute__((address_space(1))) void*)sb,
          (__attribute__((address_space(3))) void*)(Bs + j * 2048 + wave * 512), 16, 0, 0);
    }
    __syncthreads();

#pragma unroll
    for (int kh = 0; kh < 2; ++kh) {
      f16x8 bf[4];
#pragma unroll
      for (int n = 0; n < 4; ++n) {
        const int row = wc * 64 + n * 16 + c;
        bf[n] = *(const f16x8*)(Bs + (size_t)row * 64 + ((kh * 4 + g) ^ (row & 7)) * 8);
      }
#pragma unroll
      for (int m = 0; m < 4; ++m) {
        const int row = wr * 64 + m * 16 + c;
        f16x8 af = *(const f16x8*)(As + (size_t)row * 64 + ((kh * 4 + g) ^ (row & 7)) * 8);
#pragma unroll
        for (int n = 0; n < 4; ++n)
          acc[m][n] = __builtin_amdgcn_mfma_f32_16x16x32_f16(af, bf[n], acc[m][n], 0, 0, 0);
      }
    }
  }

  if (MODE == 2) {
#pragma unroll
    for (int m = 0; m < 4; ++m)
#pragma unroll
      for (int n = 0; n < 4; ++n) {
        const int gr = row0 + wr * 64 + m * 16 + g * 4;
        const int col = col0 + wc * 64 + n * 16 + c;
        const int bb = gr / NKV;
        const int kv = gr - bb * NKV;           // 4-pack cannot cross batch (784%4==0, gr%4==0)
        f16x4 pk;
#pragma unroll
        for (int r = 0; r < 4; ++r) pk[r] = (f16)(acc[m][n][r] * scale);
        *(f16x4*)(Ch + ((size_t)bb * 384 + col) * NKV + kv) = pk;
      }
  } else {
#pragma unroll
    for (int m = 0; m < 4; ++m)
#pragma unroll
      for (int n = 0; n < 4; ++n)
#pragma unroll
        for (int r = 0; r < 4; ++r) {
          const size_t row = row0 + wr * 64 + m * 16 + g * 4 + r;
          const size_t col = col0 + wc * 64 + n * 16 + c;
          if (MODE == 1) Ch[row * 384 + col] = (f16)(acc[m][n][r] * scale);
          else           Cf[row * 384 + col] = acc[m][n][r] * scale;
        }
  }
}

// fused q/k/v pointwise GEMMs: 882 flat blocks = q(196x3) + k(49x3) + v(49x3)
__global__ __launch_bounds__(256) void gemm_qkv(
    const f16* __restrict__ qdw, const f16* __restrict__ wqt, f16* __restrict__ qf, float qscale,
    const f16* __restrict__ kdw, const f16* __restrict__ wkt, f16* __restrict__ kf,
    const f16* __restrict__ vdw, const f16* __restrict__ wvt, f16* __restrict__ vtp) {
  const int blk = blockIdx.x;
  if (blk < 588) {
    gemm_body<1>(qdw, wqt, nullptr, qf, qscale, (blk % 196) * 128, (blk / 196) * 128);
  } else if (blk < 735) {
    const int r = blk - 588;
    gemm_body<1>(kdw, wkt, nullptr, kf, 1.0f, (r % 49) * 128, (r / 49) * 128);
  } else {
    const int r = blk - 735;
    gemm_body<2>(vdw, wvt, nullptr, vtp, 1.0f, (r % 49) * 128, (r / 49) * 128);
  }
}

template <int MODE>
__global__ __launch_bounds__(256) void gemm_mfma(
    const f16* __restrict__ A, const f16* __restrict__ Bt,
    float* __restrict__ Cf, f16* __restrict__ Ch, float scale) {
  gemm_body<MODE>(A, Bt, Cf, Ch, scale, blockIdx.x * 128, blockIdx.y * 128);
}

// ------------- f16 MFMA flash attention, swapped-QK^T, KVT=64, XCD-chunked, T14 -------------
__global__ __launch_bounds__(256) void attn_mfma(
    const f16* __restrict__ qp, const f16* __restrict__ kp,
    const f16* __restrict__ vt, f16* __restrict__ op) {
  __shared__ f16 Ks[64 * 64];      // [kv][d], chunk ch at ch^(kv&7)
  __shared__ f16 Vs[64 * 64];      // [d][kv], chunk ch at ch^(d&7)
  __shared__ f16 Ps[4][16 * 64];   // per-wave [q][kv], ch^(q&7)
  const int bid0 = blockIdx.x;
  const int lb = (bid0 & 7) * 294 + (bid0 >> 3);   // bijective (2352 = 8*294)
  const int qt = lb % 49;
  const int bh = lb / 49;
  const int h = bh % NHD, b = bh / NHD;
  const int tid = threadIdx.x;
  const int wave = tid >> 6, lane = tid & 63;
  const int c = lane & 15, g = lane >> 4;

  const size_t qrow = (size_t)b * NQ + qt * 64 + wave * 16 + c;
  f16x8 qa[2];
  qa[0] = *(const f16x8*)(qp + qrow * 384 + h * 64 + g * 8);
  qa[1] = *(const f16x8*)(qp + qrow * 384 + h * 64 + 32 + g * 8);

  f16x8 vones;
#pragma unroll
  for (int j = 0; j < 8; ++j) vones[j] = (f16)1.0f;

  const int tid8 = tid >> 3, tch = tid & 7;
  const int lch = tch ^ (tid8 & 7);            // logical chunk fetched

  const f16* kbase = kp + ((size_t)b * NKV) * 384 + h * 64;
  const f16* vbase = vt + ((size_t)(b * 384 + h * 64)) * NKV;

  float mrun = -1e30f;                // for q = c (redundant across g)
  f32x4 o[4] = {};                    // O[q=g*4+r][d=dt*16+c]
  f32x4 osum = {};                    // lsum[q=g*4+r]
  f16* prow = &Ps[wave][0];

  // T14 staging registers + preload tile 0
  f16x8 kr0, kr1, vr0, vr1;
  kr0 = *(const f16x8*)(kbase + (size_t)tid8 * 384 + lch * 8);
  kr1 = *(const f16x8*)(kbase + (size_t)(32 + tid8) * 384 + lch * 8);
  vr0 = *(const f16x8*)(vbase + (size_t)tid8 * NKV + lch * 8);
  vr1 = *(const f16x8*)(vbase + (size_t)(32 + tid8) * NKV + lch * 8);

  for (int ti = 0; ti < 13; ++ti) {
    __syncthreads();                  // all waves done reading LDS (prev tile)
    *(f16x8*)(Ks + tid * 8) = kr0;
    *(f16x8*)(Ks + 2048 + tid * 8) = kr1;
    *(f16x8*)(Vs + tid * 8) = vr0;
    *(f16x8*)(Vs + 2048 + tid * 8) = vr1;
    if (ti + 1 < 13) {
      const int t0n = (ti + 1) * 64;
      int kvA = t0n + tid8;        if (kvA > NKV - 1) kvA = NKV - 1;
      int kvB = t0n + 32 + tid8;   if (kvB > NKV - 1) kvB = NKV - 1;
      int colc = t0n + lch * 8;    if (colc > NKV - 8) colc = NKV - 8;
      kr0 = *(const f16x8*)(kbase + (size_t)kvA * 384 + lch * 8);
      kr1 = *(const f16x8*)(kbase + (size_t)kvB * 384 + lch * 8);
      vr0 = *(const f16x8*)(vbase + (size_t)tid8 * NKV + colc);
      vr1 = *(const f16x8*)(vbase + (size_t)(32 + tid8) * NKV + colc);
    }
    __syncthreads();                  // LDS writes visible to all waves

    if (ti < 12) {
      // -------- full tile --------
      f32x4 s[4] = {};
      __builtin_amdgcn_s_setprio(1);
#pragma unroll
      for (int kh = 0; kh < 2; ++kh) {
#pragma unroll
        for (int ct = 0; ct < 4; ++ct) {
          const int row = ct * 16 + c;
          const int sch = (kh * 4 + g) ^ (row & 7);
          f16x8 kb = *(const f16x8*)(Ks + row * 64 + sch * 8);
          s[ct] = __builtin_amdgcn_mfma_f32_16x16x32_f16(kb, qa[kh], s[ct], 0, 0, 0);
        }
      }
      __builtin_amdgcn_s_setprio(0);

      float mt = s[0][0];
#pragma unroll
      for (int ct = 0; ct < 4; ++ct)
#pragma unroll
        for (int r = 0; r < 4; ++r) mt = fmaxf(mt, s[ct][r]);
      mt = fmaxf(mt, __shfl_xor(mt, 16));
      mt = fmaxf(mt, __shfl_xor(mt, 32));

      if (__ballot(mt > mrun + 8.0f)) {   // defer-max: P bounded by 2^8
        const float mnew = fmaxf(mrun, mt);
        const float corr = fast_exp2(mrun - mnew);
        mrun = mnew;
#pragma unroll
        for (int r = 0; r < 4; ++r) {
          const float co = __shfl(corr, g * 4 + r);
#pragma unroll
          for (int dt = 0; dt < 4; ++dt) o[dt][r] *= co;
          osum[r] *= co;
        }
      }

#pragma unroll
      for (int ct = 0; ct < 4; ++ct) {
        const float p0 = fast_exp2(s[ct][0] - mrun);
        const float p1 = fast_exp2(s[ct][1] - mrun);
        const float p2 = fast_exp2(s[ct][2] - mrun);
        const float p3 = fast_exp2(s[ct][3] - mrun);
        const int sch = (ct * 2 + (g >> 1)) ^ (c & 7);
        *(f16x4*)(prow + c * 64 + sch * 8 + (g & 1) * 4) = pack4(p0, p1, p2, p3);
      }

      __builtin_amdgcn_s_setprio(1);
#pragma unroll
      for (int ks = 0; ks < 2; ++ks) {
        const int sp = (ks * 4 + g) ^ (c & 7);
        f16x8 pa = *(const f16x8*)(prow + c * 64 + sp * 8);
#pragma unroll
        for (int dt = 0; dt < 4; ++dt) {
          const int d = dt * 16 + c;
          f16x8 vb = *(const f16x8*)(Vs + d * 64 + sp * 8);
          o[dt] = __builtin_amdgcn_mfma_f32_16x16x32_f16(pa, vb, o[dt], 0, 0, 0);
        }
        osum = __builtin_amdgcn_mfma_f32_16x16x32_f16(pa, vones, osum, 0, 0, 0);
      }
      __builtin_amdgcn_s_setprio(0);
    } else {
      // -------- tail tile: t0 = 768, only 16 valid KV rows --------
      f32x4 s0 = {};
      __builtin_amdgcn_s_setprio(1);
#pragma unroll
      for (int kh = 0; kh < 2; ++kh) {
        const int sch = (kh * 4 + g) ^ (c & 7);
        f16x8 kb = *(const f16x8*)(Ks + c * 64 + sch * 8);
        s0 = __builtin_amdgcn_mfma_f32_16x16x32_f16(kb, qa[kh], s0, 0, 0, 0);
      }
      __builtin_amdgcn_s_setprio(0);

      float mt = fmaxf(fmaxf(s0[0], s0[1]), fmaxf(s0[2], s0[3]));
      mt = fmaxf(mt, __shfl_xor(mt, 16));
      mt = fmaxf(mt, __shfl_xor(mt, 32));
      if (__ballot(mt > mrun + 8.0f)) {
        const float mnew = fmaxf(mrun, mt);
        const float corr = fast_exp2(mrun - mnew);
        mrun = mnew;
#pragma unroll
        for (int r = 0; r < 4; ++r) {
          const float co = __shfl(corr, g * 4 + r);
#pragma unroll
          for (int dt = 0; dt < 4; ++dt) o[dt][r] *= co;
          osum[r] *= co;
        }
      }

      {
        const float p0 = fast_exp2(s0[0] - mrun);
        const float p1 = fast_exp2(s0[1] - mrun);
        const float p2 = fast_exp2(s0[2] - mrun);
        const float p3 = fast_exp2(s0[3] - mrun);
        const int sch0 = (0 + (g >> 1)) ^ (c & 7);
        *(f16x4*)(prow + c * 64 + sch0 * 8 + (g & 1) * 4) = pack4(p0, p1, p2, p3);
        const int sch1 = (2 + (g >> 1)) ^ (c & 7);
        f16x4 z = {};
        *(f16x4*)(prow + c * 64 + sch1 * 8 + (g & 1) * 4) = z;
      }

      __builtin_amdgcn_s_setprio(1);
      {
        const int sp = g ^ (c & 7);
        f16x8 pa = *(const f16x8*)(prow + c * 64 + sp * 8);
#pragma unroll
        for (int dt = 0; dt < 4; ++dt) {
          const int d = dt * 16 + c;
          f16x8 vb = *(const f16x8*)(Vs + d * 64 + sp * 8);
          o[dt] = __builtin_amdgcn_mfma_f32_16x16x32_f16(pa, vb, o[dt], 0, 0, 0);
        }
        osum = __builtin_amdgcn_mfma_f32_16x16x32_f16(pa, vones, osum, 0, 0, 0);
      }
      __builtin_amdgcn_s_setprio(0);
    }
  }

  // epilogue: osum already in q=g*4+r row layout -> no shuffles
  f16* obase = op + ((size_t)(b * NQ + qt * 64 + wave * 16)) * 384 + h * 64;
#pragma unroll
  for (int r = 0; r < 4; ++r) {
    const float iv = 1.0f / osum[r];
#pragma unroll
    for (int dt = 0; dt < 4; ++dt)
      obase[(size_t)(g * 4 + r) * 384 + dt * 16 + c] = (f16)(o[dt][r] * iv);
  }
}

extern "C" void kernel_launch(void* const* d_in, const int* in_sizes, int n_in,
                              void* d_out, int out_size, void* d_ws, size_t ws_size,
                              hipStream_t stream) {
  const float* inputs_q  = (const float*)d_in[0];
  const float* inputs_kv = (const float*)d_in[1];
  const float* out_kern  = (const float*)d_in[2];
  const float* q_dwk = (const float*)d_in[3];
  const float* q_bs  = (const float*)d_in[4];
  const float* q_bb  = (const float*)d_in[5];
  const float* q_bm  = (const float*)d_in[6];
  const float* q_bv  = (const float*)d_in[7];
  const float* q_pwk = (const float*)d_in[8];
  const float* k_dwk = (const float*)d_in[9];
  const float* k_bs  = (const float*)d_in[10];
  const float* k_bb  = (const float*)d_in[11];
  const float* k_bm  = (const float*)d_in[12];
  const float* k_bv  = (const float*)d_in[13];
  const float* k_pwk = (const float*)d_in[14];
  const float* v_dwk = (const float*)d_in[15];
  const float* v_bs  = (const float*)d_in[16];
  const float* v_bb  = (const float*)d_in[17];
  const float* v_bm  = (const float*)d_in[18];
  const float* v_bv  = (const float*)d_in[19];
  const float* v_pwk = (const float*)d_in[20];

  char* wsb = (char*)d_ws;
  f16* qdw = (f16*)(wsb + 0);             // 25088*384 f16
  f16* kdw = (f16*)(wsb + 19267584);      // 6272*384 f16
  f16* vdw = (f16*)(wsb + 24084480);      // 6272*384 f16
  f16* qf  = (f16*)(wsb + 28901376);      // 25088*384 f16
  f16* kf  = (f16*)(wsb + 48168960);      // 6272*384 f16
  f16* vtp = (f16*)(wsb + 57802752);      // 8*384*784 f16
  f16* of  = (f16*)(wsb + 62619648);      // 25088*384 f16
  f16* wqt = (f16*)(wsb + 81887232);      // 384*384 f16 x4
  f16* wkt = (f16*)(wsb + 82182144);
  f16* wvt = (f16*)(wsb + 82477056);
  f16* wot = (f16*)(wsb + 82771968);

  // 1. fused preprocess (XCD-chunked, high-ILP dw bodies)
  preprocess<<<4104, 256, 0, stream>>>(
      inputs_q, inputs_kv,
      q_dwk, q_bs, q_bb, q_bm, q_bv,
      k_dwk, k_bs, k_bb, k_bm, k_bv,
      v_dwk, v_bs, v_bb, v_bm, v_bv,
      q_pwk, k_pwk, v_pwk, out_kern, wqt, wkt, wvt, wot,
      qdw, kdw, vdw);
  // 2. fused q/k/v pointwise GEMMs (V written transposed; q folded with 1/8*log2e)
  gemm_qkv<<<882, 256, 0, stream>>>(qdw, wqt, qf, 0.125f * LOG2E,
                                    kdw, wkt, kf, vdw, wvt, vtp);
  // 3. MFMA attention (KVT=64, XCD-chunked, T14 async-STAGE, specialized tail) -> f16 O
  attn_mfma<<<BB * NHD * 49, 256, 0, stream>>>(qf, kf, vtp, of);
  // 4. output projection (MFMA, fp32 out)
  gemm_mfma<0><<<dim3(196, 3), 256, 0, stream>>>(of, wot, (float*)d_out, nullptr, 1.0f);
}